// Round 2
// baseline (1435.786 us; speedup 1.0000x reference)
//
#include <hip/hip_runtime.h>
#include <math.h>

#define NT 262144
#define NS 512
#define ES 2097152
#define EO 8192
#define NLAYER 4

typedef short bf16x8 __attribute__((ext_vector_type(8)));
typedef float f32x16 __attribute__((ext_vector_type(16)));

__device__ inline unsigned short rne_bf16(float f) {
    unsigned int u = __float_as_uint(f);
    u += 0x7FFF + ((u >> 16) & 1);
    return (unsigned short)(u >> 16);
}

// ---------------- CSR build (big graph) ----------------
__global__ void hist_kernel(const int* __restrict__ dst, int* __restrict__ deg) {
    int e = blockIdx.x * 256 + threadIdx.x;
    if (e < ES) atomicAdd(&deg[dst[e]], 1);
}

__global__ void scan1_kernel(const int* __restrict__ deg, int* __restrict__ rowptr,
                             int* __restrict__ bsum) {
    __shared__ int lds[1024];
    int t = threadIdx.x;
    int g = blockIdx.x * 1024 + t;
    int v = deg[g];
    lds[t] = v;
    __syncthreads();
    for (int off = 1; off < 1024; off <<= 1) {
        int x = (t >= off) ? lds[t - off] : 0;
        __syncthreads();
        lds[t] += x;
        __syncthreads();
    }
    rowptr[g] = lds[t] - v;
    if (t == 1023) bsum[blockIdx.x] = lds[t];
}

__global__ void scan2_kernel(int* bsum) {
    __shared__ int lds[256];
    int t = threadIdx.x;
    int v = bsum[t];
    lds[t] = v;
    __syncthreads();
    for (int off = 1; off < 256; off <<= 1) {
        int x = (t >= off) ? lds[t - off] : 0;
        __syncthreads();
        lds[t] += x;
        __syncthreads();
    }
    bsum[t] = lds[t] - v;
}

__global__ void scan3_kernel(int* __restrict__ rowptr, const int* __restrict__ bsum,
                             int* __restrict__ cursor) {
    int t = threadIdx.x;
    int g = blockIdx.x * 1024 + t;
    int v = rowptr[g] + bsum[blockIdx.x];
    rowptr[g] = v;
    cursor[g] = v;
    if (g == NT - 1) rowptr[NT] = ES;
}

__global__ void scatter_kernel(const int* __restrict__ ei, int* __restrict__ cursor,
                               int* __restrict__ srcs) {
    int e = blockIdx.x * 256 + threadIdx.x;
    if (e < ES) {
        int d = ei[ES + e];
        int pos = atomicAdd(&cursor[d], 1);
        srcs[pos] = ei[e];
    }
}

// ---------------- CSR build (small graph, single block) ----------------
__global__ void small_csr_kernel(const int* __restrict__ oei, int* __restrict__ rowptrS,
                                 int* __restrict__ srcsS) {
    __shared__ int sdeg[NS];
    __shared__ int scur[NS];
    int t = threadIdx.x;
    if (t < NS) sdeg[t] = 0;
    __syncthreads();
    for (int e = t; e < EO; e += 1024) atomicAdd(&sdeg[oei[EO + e]], 1);
    __syncthreads();
    int myv = (t < NS) ? sdeg[t] : 0;
    __syncthreads();
    for (int off = 1; off < NS; off <<= 1) {
        int x = (t >= off && t < NS) ? sdeg[t - off] : 0;
        __syncthreads();
        if (t < NS) sdeg[t] += x;
        __syncthreads();
    }
    if (t < NS) {
        int excl = sdeg[t] - myv;
        rowptrS[t] = excl;
        scur[t] = excl;
        if (t == 0) rowptrS[NS] = EO;
    }
    __syncthreads();
    for (int e = t; e < EO; e += 1024) {
        int d = oei[EO + e];
        int pos = atomicAdd(&scur[d], 1);
        srcsS[pos] = oei[e];
    }
}

// ---------------- MFMA gconv (big graph) ----------------
// block = 256 threads (4 waves), 64 nodes/block.
// wave w: node-tile nt=w>>1 (rows nt*32..+31), col-tile ct=w&1 (cols ct*32..+31).
// A = [agg | h] (64x128) split bf16 hi/lo in LDS (XOR-swizzled 16B groups).
// B = [Wr;Wt] column per output col, split bf16 hi/lo held in VGPR frags.
// C = 32x32 f32 tile; 3 MFMAs per k-chunk (hh, lh, hl) => f32-grade precision.
__global__ __launch_bounds__(256, 4) void gconv_mfma_kernel(
    const float* __restrict__ hin, const int* __restrict__ rowptr, const int* __restrict__ srcs,
    const float* __restrict__ Wr, const float* __restrict__ Wt, const float* __restrict__ br,
    float* __restrict__ hout, float* __restrict__ stats)
{
    __shared__ unsigned short Ahi[64 * 128];   // 16 KB
    __shared__ unsigned short Alo[64 * 128];   // 16 KB

    int tid = threadIdx.x;
    int w = tid >> 6;
    int l = tid & 63;
    int nt = w >> 1;
    int ct = w & 1;
    int n_out = ct * 32 + (l & 31);

    // ---- B fragments from global, split hi/lo ----
    bf16x8 Bh[8], Bl[8];
    #pragma unroll
    for (int kc = 0; kc < 8; kc++) {
        int kbase = kc * 16 + ((l >> 5) << 3);
        const float* wsrc = (kbase < 64) ? (Wr + n_out * 64 + kbase)
                                         : (Wt + n_out * 64 + (kbase - 64));
        float4 u0 = *(const float4*)(wsrc);
        float4 u1 = *(const float4*)(wsrc + 4);
        float vv[8] = {u0.x, u0.y, u0.z, u0.w, u1.x, u1.y, u1.z, u1.w};
        #pragma unroll
        for (int j = 0; j < 8; j++) {
            unsigned short hi = rne_bf16(vv[j]);
            float hif = __uint_as_float((unsigned int)hi << 16);
            Bh[kc][j] = (short)hi;
            Bl[kc][j] = (short)rne_bf16(vv[j] - hif);
        }
    }
    float bias = br[n_out];

    // ---- gather phase: wave w handles 16 nodes, lane = column ----
    int node0 = blockIdx.x * 64 + w * 16;
    for (int r = 0; r < 16; r++) {
        int node = node0 + r;
        float hown = hin[node * 64 + l];
        int e0 = rowptr[node], e1 = rowptr[node + 1];
        float a = 0.f;
        int e = e0;
        for (; e + 4 <= e1; e += 4) {
            int s0 = srcs[e], s1 = srcs[e + 1], s2 = srcs[e + 2], s3 = srcs[e + 3];
            float v0 = hin[s0 * 64 + l];
            float v1 = hin[s1 * 64 + l];
            float v2 = hin[s2 * 64 + l];
            float v3 = hin[s3 * 64 + l];
            a += (v0 + v1) + (v2 + v3);
        }
        for (; e < e1; e++) a += hin[srcs[e] * 64 + l];

        int row = w * 16 + r;
        // agg at k=l
        {
            int k = l;
            int g = k >> 3;
            int off = row * 128 + (((g ^ (row & 15)) << 3) | (k & 7));
            unsigned short hi = rne_bf16(a);
            float hif = __uint_as_float((unsigned int)hi << 16);
            Ahi[off] = hi;
            Alo[off] = rne_bf16(a - hif);
        }
        // own h at k=64+l
        {
            int k = 64 + l;
            int g = k >> 3;
            int off = row * 128 + (((g ^ (row & 15)) << 3) | (k & 7));
            unsigned short hi = rne_bf16(hown);
            float hif = __uint_as_float((unsigned int)hi << 16);
            Ahi[off] = hi;
            Alo[off] = rne_bf16(hown - hif);
        }
    }
    __syncthreads();

    // ---- MFMA phase ----
    f32x16 acc;
    #pragma unroll
    for (int j = 0; j < 16; j++) acc[j] = bias;

    int row = nt * 32 + (l & 31);
    #pragma unroll
    for (int kc = 0; kc < 8; kc++) {
        int g = kc * 2 + (l >> 5);
        int off = row * 128 + ((g ^ (row & 15)) << 3);
        bf16x8 ah = *(const bf16x8*)(Ahi + off);
        bf16x8 al = *(const bf16x8*)(Alo + off);
        acc = __builtin_amdgcn_mfma_f32_32x32x16_bf16(ah, Bh[kc], acc, 0, 0, 0);
        acc = __builtin_amdgcn_mfma_f32_32x32x16_bf16(al, Bh[kc], acc, 0, 0, 0);
        acc = __builtin_amdgcn_mfma_f32_32x32x16_bf16(ah, Bl[kc], acc, 0, 0, 0);
    }

    // ---- epilogue: store h1 + BN stats ----
    float s = 0.f, q = 0.f;
    #pragma unroll
    for (int j = 0; j < 16; j++) {
        int crow = (j & 3) + 8 * (j >> 2) + 4 * (l >> 5);
        int node = blockIdx.x * 64 + nt * 32 + crow;
        float v = acc[j];
        hout[node * 64 + n_out] = v;
        s += v;
        q += v * v;
    }
    s += __shfl_xor(s, 32, 64);
    q += __shfl_xor(q, 32, 64);
    int rep = blockIdx.x & 31;
    if ((l & 32) == 0) {
        atomicAdd(&stats[rep * 128 + n_out], s);
        atomicAdd(&stats[rep * 128 + 64 + n_out], q);
    }
}

// ---------------- old VALU gconv (kept for the 512-node small graph) ----------
__global__ __launch_bounds__(512, 6) void gconv_kernel(
    const float* __restrict__ hin, const int* __restrict__ rowptr, const int* __restrict__ srcs,
    const float* __restrict__ Wr, const float* __restrict__ Wt, const float* __restrict__ br,
    float* __restrict__ hout, float* __restrict__ stats)
{
    __shared__ float wrt[4096];
    __shared__ float wtt[4096];
    __shared__ float4 aggT[8][64];
    __shared__ float4 hT[8][64];
    __shared__ float sbuf[8][64];
    __shared__ float qbuf[8][64];
    __shared__ float brs[64];

    int tid = threadIdx.x;
    for (int idx = tid; idx < 4096; idx += 512) {
        int cc = idx >> 6, kk = idx & 63;
        wrt[kk * 64 + ((kk + cc) & 63)] = Wr[idx];
        wtt[kk * 64 + ((kk + cc) & 63)] = Wt[idx];
    }
    if (tid < 64) brs[tid] = br[tid];
    __syncthreads();

    int w = tid >> 6;
    int c = tid & 63;
    int node0 = (blockIdx.x * 8 + w) * 4;

    float* aggp = (float*)&aggT[w][0];
    float* hp   = (float*)&hT[w][0];
    #pragma unroll
    for (int r = 0; r < 4; r++) {
        int node = node0 + r;
        hp[c * 4 + r] = hin[node * 64 + c];
        int e0 = rowptr[node], e1 = rowptr[node + 1];
        float a = 0.f;
        int e = e0;
        for (; e + 4 <= e1; e += 4) {
            int s0 = srcs[e], s1 = srcs[e + 1], s2 = srcs[e + 2], s3 = srcs[e + 3];
            float v0 = hin[s0 * 64 + c];
            float v1 = hin[s1 * 64 + c];
            float v2 = hin[s2 * 64 + c];
            float v3 = hin[s3 * 64 + c];
            a += (v0 + v1) + (v2 + v3);
        }
        for (; e < e1; e++) a += hin[srcs[e] * 64 + c];
        aggp[c * 4 + r] = a;
    }

    float o0 = brs[c], o1 = o0, o2 = o0, o3 = o0;
    #pragma unroll 8
    for (int k = 0; k < 64; k++) {
        float wr = wrt[k * 64 + ((k + c) & 63)];
        float wt = wtt[k * 64 + ((k + c) & 63)];
        float4 av = aggT[w][k];
        float4 hv = hT[w][k];
        o0 += wr * av.x + wt * hv.x;
        o1 += wr * av.y + wt * hv.y;
        o2 += wr * av.z + wt * hv.z;
        o3 += wr * av.w + wt * hv.w;
    }
    hout[(node0 + 0) * 64 + c] = o0;
    hout[(node0 + 1) * 64 + c] = o1;
    hout[(node0 + 2) * 64 + c] = o2;
    hout[(node0 + 3) * 64 + c] = o3;

    sbuf[w][c] = (o0 + o1) + (o2 + o3);
    qbuf[w][c] = (o0 * o0 + o1 * o1) + (o2 * o2 + o3 * o3);
    __syncthreads();
    int rep = blockIdx.x & 31;
    if (w == 0) {
        float s = 0.f;
        #pragma unroll
        for (int ww = 0; ww < 8; ww++) s += sbuf[ww][c];
        atomicAdd(&stats[rep * 128 + c], s);
    } else if (w == 1) {
        float q = 0.f;
        #pragma unroll
        for (int ww = 0; ww < 8; ww++) q += qbuf[ww][c];
        atomicAdd(&stats[rep * 128 + 64 + c], q);
    }
}

// ---------------- subgraph mean ----------------
__global__ void smean_kernel(const float* __restrict__ hin, float* __restrict__ xsum) {
    __shared__ float red[16][64];
    int t = threadIdx.x;
    int w = t >> 6, c = t & 63;
    int n = blockIdx.x;
    int base = n * 64 + c;
    float s = 0.f;
    #pragma unroll 8
    for (int j = 0; j < 32; j++) {
        int si = w * 32 + j;
        s += hin[si * 32768 + base];
    }
    red[w][c] = s;
    __syncthreads();
    if (w == 0) {
        float tot = 0.f;
        #pragma unroll
        for (int ww = 0; ww < 16; ww++) tot += red[ww][c];
        xsum[base] = tot * (1.f / 512.f);
    }
}

// ---------------- fold BN stats into per-column scale/shift ----------------
__global__ void finalize_kernel(const float* __restrict__ stB, const float* __restrict__ stS,
                                const float* __restrict__ gB, const float* __restrict__ bB,
                                const float* __restrict__ gS, const float* __restrict__ bS,
                                float* __restrict__ bnp) {
    int c = threadIdx.x;
    float sb = 0.f, qb = 0.f, ss = 0.f, qs = 0.f;
    for (int r = 0; r < 32; r++) {
        sb += stB[r * 128 + c];
        qb += stB[r * 128 + 64 + c];
        ss += stS[r * 128 + c];
        qs += stS[r * 128 + 64 + c];
    }
    float muB = sb * (1.f / 262144.f);
    float varB = qb * (1.f / 262144.f) - muB * muB;
    float scB = gB[c] * rsqrtf(varB + 1e-5f);
    bnp[c] = scB;
    bnp[64 + c] = bB[c] - muB * scB;
    float muS = ss * (1.f / 512.f);
    float varS = qs * (1.f / 512.f) - muS * muS;
    float scS = gS[c] * rsqrtf(varS + 1e-5f);
    bnp[128 + c] = scS;
    bnp[192 + c] = bS[c] - muS * scS;
}

// ---------------- h = relu(bn(h1) + bn(h2)[t % 512]) ----------------
__global__ void combine_kernel(const float* __restrict__ h1, const float* __restrict__ h2,
                               const float* __restrict__ bnp, float* __restrict__ hout) {
    int idx = blockIdx.x * 256 + threadIdx.x;
    int base = idx * 4;
    int c = base & 63;
    int t = base >> 6;
    int n = t & 511;
    float4 a = *(const float4*)(h1 + base);
    float4 b = *(const float4*)(h2 + n * 64 + c);
    float4 sB = *(const float4*)(bnp + c);
    float4 hB = *(const float4*)(bnp + 64 + c);
    float4 sS = *(const float4*)(bnp + 128 + c);
    float4 hS = *(const float4*)(bnp + 192 + c);
    float4 r;
    r.x = fmaxf(a.x * sB.x + hB.x + b.x * sS.x + hS.x, 0.f);
    r.y = fmaxf(a.y * sB.y + hB.y + b.y * sS.y + hS.y, 0.f);
    r.z = fmaxf(a.z * sB.z + hB.z + b.z * sS.z + hS.z, 0.f);
    r.w = fmaxf(a.w * sB.w + hB.w + b.w * sS.w + hS.w, 0.f);
    *(float4*)(hout + base) = r;
}

// ---------------- head ----------------
__global__ void head_kernel(const float* __restrict__ xs, const float* __restrict__ W1,
                            const float* __restrict__ b1, const float* __restrict__ W2,
                            const float* __restrict__ b2, float* __restrict__ out) {
    __shared__ float z[64];
    __shared__ float hid[128];
    int t = threadIdx.x;
    int n = blockIdx.x;
    if (t < 64) {
        float v = xs[n * 64 + t];
        float m = v;
        for (int off = 32; off >= 1; off >>= 1) m = fmaxf(m, __shfl_xor(m, off, 64));
        float e = expf(v - m);
        float s = e;
        for (int off = 32; off >= 1; off >>= 1) s += __shfl_xor(s, off, 64);
        z[t] = v - m - logf(s);
    }
    __syncthreads();
    {
        float acc = b1[t];
        const float* wrow = W1 + t * 64;
        #pragma unroll 8
        for (int k = 0; k < 64; k++) acc += z[k] * wrow[k];
        hid[t] = fmaxf(acc, 0.f);
    }
    __syncthreads();
    if (t < 10) {
        float o = b2[t];
        const float* wrow = W2 + t * 128;
        #pragma unroll 8
        for (int j = 0; j < 128; j++) o += hid[j] * wrow[j];
        out[n * 10 + t] = o;
    }
}

extern "C" void kernel_launch(void* const* d_in, const int* in_sizes, int n_in,
                              void* d_out, int out_size, void* d_ws, size_t ws_size,
                              hipStream_t stream) {
    const float* x       = (const float*)d_in[0];
    const float* Wrel    = (const float*)d_in[1];
    const float* brel    = (const float*)d_in[2];
    const float* Wroot   = (const float*)d_in[3];
    const float* bn_g    = (const float*)d_in[4];
    const float* bn_b    = (const float*)d_in[5];
    const float* Wrel_s  = (const float*)d_in[6];
    const float* brel_s  = (const float*)d_in[7];
    const float* Wroot_s = (const float*)d_in[8];
    const float* bns_g   = (const float*)d_in[9];
    const float* bns_b   = (const float*)d_in[10];
    const float* W1      = (const float*)d_in[11];
    const float* b1      = (const float*)d_in[12];
    const float* W2      = (const float*)d_in[13];
    const float* b2      = (const float*)d_in[14];
    const int* ei        = (const int*)d_in[15];
    const int* oei       = (const int*)d_in[16];
    float* out = (float*)d_out;

    char* ws = (char*)d_ws;
    size_t off = 0;
    auto alloc = [&](size_t bytes) -> void* {
        void* p = ws + off;
        off = (off + bytes + 255) & ~(size_t)255;
        return p;
    };
    float* h     = (float*)alloc((size_t)NT * 64 * 4);
    float* h1    = (float*)alloc((size_t)NT * 64 * 4);
    float* xsum  = (float*)alloc(NS * 64 * 4);
    float* h2    = (float*)alloc(NS * 64 * 4);
    float* stats = (float*)alloc(NLAYER * 2 * 4096 * 4);
    float* bnp   = (float*)alloc(256 * 4);
    int* rowptr  = (int*)alloc((size_t)(NT + 1) * 4);
    int* cursor  = (int*)alloc((size_t)NT * 4);
    int* srcs    = (int*)alloc((size_t)ES * 4);
    int* bsum    = (int*)alloc(256 * 4);
    int* rowptrS = (int*)alloc(513 * 4);
    int* srcsS   = (int*)alloc(EO * 4);
    (void)ws_size; (void)in_sizes; (void)n_in; (void)out_size;

    hipMemsetAsync(cursor, 0, (size_t)NT * 4, stream);
    hipMemsetAsync(stats, 0, (size_t)NLAYER * 2 * 4096 * 4, stream);

    hist_kernel<<<ES / 256, 256, 0, stream>>>(ei + ES, cursor);
    scan1_kernel<<<NT / 1024, 1024, 0, stream>>>(cursor, rowptr, bsum);
    scan2_kernel<<<1, 256, 0, stream>>>(bsum);
    scan3_kernel<<<NT / 1024, 1024, 0, stream>>>(rowptr, bsum, cursor);
    scatter_kernel<<<ES / 256, 256, 0, stream>>>(ei, cursor, srcs);
    small_csr_kernel<<<1, 1024, 0, stream>>>(oei, rowptrS, srcsS);

    for (int i = 0; i < NLAYER; i++) {
        const float* hin = (i == 0) ? x : h;
        float* stB = stats + i * 8192;
        float* stS = stB + 4096;
        smean_kernel<<<NS, 1024, 0, stream>>>(hin, xsum);
        gconv_mfma_kernel<<<NT / 64, 256, 0, stream>>>(hin, rowptr, srcs,
            Wrel + i * 4096, Wroot + i * 4096, brel + i * 64, h1, stB);
        gconv_kernel<<<NS / 32, 512, 0, stream>>>(xsum, rowptrS, srcsS,
            Wrel_s + i * 4096, Wroot_s + i * 4096, brel_s + i * 64, h2, stS);
        finalize_kernel<<<1, 64, 0, stream>>>(stB, stS, bn_g + i * 64, bn_b + i * 64,
                                              bns_g + i * 64, bns_b + i * 64, bnp);
        combine_kernel<<<NT * 64 / 4 / 256, 256, 0, stream>>>(h1, h2, bnp, h);
    }
    smean_kernel<<<NS, 1024, 0, stream>>>(h, xsum);
    head_kernel<<<NS, 128, 0, stream>>>(xsum, W1, b1, W2, b2, out);
}

// Round 3
// 1257.901 us; speedup vs baseline: 1.1414x; 1.1414x over previous
//
#include <hip/hip_runtime.h>
#include <math.h>

#define NT 262144
#define NS 512
#define ES 2097152
#define EO 8192
#define NLAYER 4

typedef short bf16x8 __attribute__((ext_vector_type(8)));
typedef float f32x16 __attribute__((ext_vector_type(16)));

__device__ inline unsigned short rne_bf16(float f) {
    unsigned int u = __float_as_uint(f);
    u += 0x7FFF + ((u >> 16) & 1);
    return (unsigned short)(u >> 16);
}

// ---------------- CSR build (big graph) ----------------
__global__ void hist_kernel(const int* __restrict__ dst, int* __restrict__ deg) {
    int e = blockIdx.x * 256 + threadIdx.x;
    if (e < ES) atomicAdd(&deg[dst[e]], 1);
}

__global__ void scan1_kernel(const int* __restrict__ deg, int* __restrict__ rowptr,
                             int* __restrict__ bsum) {
    __shared__ int lds[1024];
    int t = threadIdx.x;
    int g = blockIdx.x * 1024 + t;
    int v = deg[g];
    lds[t] = v;
    __syncthreads();
    for (int off = 1; off < 1024; off <<= 1) {
        int x = (t >= off) ? lds[t - off] : 0;
        __syncthreads();
        lds[t] += x;
        __syncthreads();
    }
    rowptr[g] = lds[t] - v;
    if (t == 1023) bsum[blockIdx.x] = lds[t];
}

__global__ void scan2_kernel(int* bsum) {
    __shared__ int lds[256];
    int t = threadIdx.x;
    int v = bsum[t];
    lds[t] = v;
    __syncthreads();
    for (int off = 1; off < 256; off <<= 1) {
        int x = (t >= off) ? lds[t - off] : 0;
        __syncthreads();
        lds[t] += x;
        __syncthreads();
    }
    bsum[t] = lds[t] - v;
}

__global__ void scan3_kernel(int* __restrict__ rowptr, const int* __restrict__ bsum,
                             int* __restrict__ cursor) {
    int t = threadIdx.x;
    int g = blockIdx.x * 1024 + t;
    int v = rowptr[g] + bsum[blockIdx.x];
    rowptr[g] = v;
    cursor[g] = v;
    if (g == NT - 1) rowptr[NT] = ES;
}

__global__ void scatter_kernel(const int* __restrict__ ei, int* __restrict__ cursor,
                               int* __restrict__ srcs) {
    int e = blockIdx.x * 256 + threadIdx.x;
    if (e < ES) {
        int d = ei[ES + e];
        int pos = atomicAdd(&cursor[d], 1);
        srcs[pos] = ei[e];
    }
}

// ---------------- CSR build (small graph, single block) ----------------
__global__ void small_csr_kernel(const int* __restrict__ oei, int* __restrict__ rowptrS,
                                 int* __restrict__ srcsS) {
    __shared__ int sdeg[NS];
    __shared__ int scur[NS];
    int t = threadIdx.x;
    if (t < NS) sdeg[t] = 0;
    __syncthreads();
    for (int e = t; e < EO; e += 1024) atomicAdd(&sdeg[oei[EO + e]], 1);
    __syncthreads();
    int myv = (t < NS) ? sdeg[t] : 0;
    __syncthreads();
    for (int off = 1; off < NS; off <<= 1) {
        int x = (t >= off && t < NS) ? sdeg[t - off] : 0;
        __syncthreads();
        if (t < NS) sdeg[t] += x;
        __syncthreads();
    }
    if (t < NS) {
        int excl = sdeg[t] - myv;
        rowptrS[t] = excl;
        scur[t] = excl;
        if (t == 0) rowptrS[NS] = EO;
    }
    __syncthreads();
    for (int e = t; e < EO; e += 1024) {
        int d = oei[EO + e];
        int pos = atomicAdd(&scur[d], 1);
        srcsS[pos] = oei[e];
    }
}

// ---------------- MFMA gconv (big graph) ----------------
// Physical block id is remapped so the 8 blocks covering one subgraph occupy
// 8 CONSECUTIVE-PER-XCD ids: p = (sub%8) + 8*((sub/8)*8 + tile). Both known
// blockIdx->XCD mappings (round-robin %8 and contiguous chunks) then place all
// 8 tiles of a subgraph on the same XCD, back-to-back in time, so the gather
// reads hit that XCD's L2 (subgraph window = 128 KB; ~13 windows in flight/XCD
// = 1.7 MB < 4 MB L2).
__global__ __launch_bounds__(256, 4) void gconv_mfma_kernel(
    const float* __restrict__ hin, const int* __restrict__ rowptr, const int* __restrict__ srcs,
    const float* __restrict__ Wr, const float* __restrict__ Wt, const float* __restrict__ br,
    float* __restrict__ hout, float* __restrict__ stats)
{
    __shared__ unsigned short Ahi[64 * 128];   // 16 KB
    __shared__ unsigned short Alo[64 * 128];   // 16 KB

    int p = blockIdx.x;
    int x = p & 7;
    int q = p >> 3;          // 0..511
    int sub = x + 8 * (q >> 3);
    int tile = q & 7;
    int nb = sub * 512 + tile * 64;   // first node of this block

    int tid = threadIdx.x;
    int w = tid >> 6;
    int l = tid & 63;
    int nt = w >> 1;
    int ct = w & 1;
    int n_out = ct * 32 + (l & 31);

    // ---- B fragments from global, split hi/lo ----
    bf16x8 Bh[8], Bl[8];
    #pragma unroll
    for (int kc = 0; kc < 8; kc++) {
        int kbase = kc * 16 + ((l >> 5) << 3);
        const float* wsrc = (kbase < 64) ? (Wr + n_out * 64 + kbase)
                                         : (Wt + n_out * 64 + (kbase - 64));
        float4 u0 = *(const float4*)(wsrc);
        float4 u1 = *(const float4*)(wsrc + 4);
        float vv[8] = {u0.x, u0.y, u0.z, u0.w, u1.x, u1.y, u1.z, u1.w};
        #pragma unroll
        for (int j = 0; j < 8; j++) {
            unsigned short hi = rne_bf16(vv[j]);
            float hif = __uint_as_float((unsigned int)hi << 16);
            Bh[kc][j] = (short)hi;
            Bl[kc][j] = (short)rne_bf16(vv[j] - hif);
        }
    }
    float bias = br[n_out];

    // ---- gather phase: wave w handles 16 nodes, lane = column ----
    int node0 = nb + w * 16;
    for (int r = 0; r < 16; r++) {
        int node = node0 + r;
        float hown = hin[node * 64 + l];
        int e0 = rowptr[node], e1 = rowptr[node + 1];
        float a = 0.f;
        int e = e0;
        for (; e + 4 <= e1; e += 4) {
            int s0 = srcs[e], s1 = srcs[e + 1], s2 = srcs[e + 2], s3 = srcs[e + 3];
            float v0 = hin[s0 * 64 + l];
            float v1 = hin[s1 * 64 + l];
            float v2 = hin[s2 * 64 + l];
            float v3 = hin[s3 * 64 + l];
            a += (v0 + v1) + (v2 + v3);
        }
        for (; e < e1; e++) a += hin[srcs[e] * 64 + l];

        int row = w * 16 + r;
        {
            int k = l;
            int g = k >> 3;
            int off = row * 128 + (((g ^ (row & 15)) << 3) | (k & 7));
            unsigned short hi = rne_bf16(a);
            float hif = __uint_as_float((unsigned int)hi << 16);
            Ahi[off] = hi;
            Alo[off] = rne_bf16(a - hif);
        }
        {
            int k = 64 + l;
            int g = k >> 3;
            int off = row * 128 + (((g ^ (row & 15)) << 3) | (k & 7));
            unsigned short hi = rne_bf16(hown);
            float hif = __uint_as_float((unsigned int)hi << 16);
            Ahi[off] = hi;
            Alo[off] = rne_bf16(hown - hif);
        }
    }
    __syncthreads();

    // ---- MFMA phase ----
    f32x16 acc;
    #pragma unroll
    for (int j = 0; j < 16; j++) acc[j] = bias;

    int row = nt * 32 + (l & 31);
    #pragma unroll
    for (int kc = 0; kc < 8; kc++) {
        int g = kc * 2 + (l >> 5);
        int off = row * 128 + ((g ^ (row & 15)) << 3);
        bf16x8 ah = *(const bf16x8*)(Ahi + off);
        bf16x8 al = *(const bf16x8*)(Alo + off);
        acc = __builtin_amdgcn_mfma_f32_32x32x16_bf16(ah, Bh[kc], acc, 0, 0, 0);
        acc = __builtin_amdgcn_mfma_f32_32x32x16_bf16(al, Bh[kc], acc, 0, 0, 0);
        acc = __builtin_amdgcn_mfma_f32_32x32x16_bf16(ah, Bl[kc], acc, 0, 0, 0);
    }

    // ---- epilogue: store h1 + BN stats ----
    float s = 0.f, qv = 0.f;
    #pragma unroll
    for (int j = 0; j < 16; j++) {
        int crow = (j & 3) + 8 * (j >> 2) + 4 * (l >> 5);
        int node = nb + nt * 32 + crow;
        float v = acc[j];
        hout[node * 64 + n_out] = v;
        s += v;
        qv += v * v;
    }
    s += __shfl_xor(s, 32, 64);
    qv += __shfl_xor(qv, 32, 64);
    int rep = p & 31;
    if ((l & 32) == 0) {
        atomicAdd(&stats[rep * 128 + n_out], s);
        atomicAdd(&stats[rep * 128 + 64 + n_out], qv);
    }
}

// ---------------- VALU gconv (512-node small graph) ----------
__global__ __launch_bounds__(512, 6) void gconv_kernel(
    const float* __restrict__ hin, const int* __restrict__ rowptr, const int* __restrict__ srcs,
    const float* __restrict__ Wr, const float* __restrict__ Wt, const float* __restrict__ br,
    float* __restrict__ hout, float* __restrict__ stats)
{
    __shared__ float wrt[4096];
    __shared__ float wtt[4096];
    __shared__ float4 aggT[8][64];
    __shared__ float4 hT[8][64];
    __shared__ float sbuf[8][64];
    __shared__ float qbuf[8][64];
    __shared__ float brs[64];

    int tid = threadIdx.x;
    for (int idx = tid; idx < 4096; idx += 512) {
        int cc = idx >> 6, kk = idx & 63;
        wrt[kk * 64 + ((kk + cc) & 63)] = Wr[idx];
        wtt[kk * 64 + ((kk + cc) & 63)] = Wt[idx];
    }
    if (tid < 64) brs[tid] = br[tid];
    __syncthreads();

    int w = tid >> 6;
    int c = tid & 63;
    int node0 = (blockIdx.x * 8 + w) * 4;

    float* aggp = (float*)&aggT[w][0];
    float* hp   = (float*)&hT[w][0];
    #pragma unroll
    for (int r = 0; r < 4; r++) {
        int node = node0 + r;
        hp[c * 4 + r] = hin[node * 64 + c];
        int e0 = rowptr[node], e1 = rowptr[node + 1];
        float a = 0.f;
        int e = e0;
        for (; e + 4 <= e1; e += 4) {
            int s0 = srcs[e], s1 = srcs[e + 1], s2 = srcs[e + 2], s3 = srcs[e + 3];
            float v0 = hin[s0 * 64 + c];
            float v1 = hin[s1 * 64 + c];
            float v2 = hin[s2 * 64 + c];
            float v3 = hin[s3 * 64 + c];
            a += (v0 + v1) + (v2 + v3);
        }
        for (; e < e1; e++) a += hin[srcs[e] * 64 + c];
        aggp[c * 4 + r] = a;
    }

    float o0 = brs[c], o1 = o0, o2 = o0, o3 = o0;
    #pragma unroll 8
    for (int k = 0; k < 64; k++) {
        float wr = wrt[k * 64 + ((k + c) & 63)];
        float wt = wtt[k * 64 + ((k + c) & 63)];
        float4 av = aggT[w][k];
        float4 hv = hT[w][k];
        o0 += wr * av.x + wt * hv.x;
        o1 += wr * av.y + wt * hv.y;
        o2 += wr * av.z + wt * hv.z;
        o3 += wr * av.w + wt * hv.w;
    }
    hout[(node0 + 0) * 64 + c] = o0;
    hout[(node0 + 1) * 64 + c] = o1;
    hout[(node0 + 2) * 64 + c] = o2;
    hout[(node0 + 3) * 64 + c] = o3;

    sbuf[w][c] = (o0 + o1) + (o2 + o3);
    qbuf[w][c] = (o0 * o0 + o1 * o1) + (o2 * o2 + o3 * o3);
    __syncthreads();
    int rep = blockIdx.x & 31;
    if (w == 0) {
        float s = 0.f;
        #pragma unroll
        for (int ww = 0; ww < 8; ww++) s += sbuf[ww][c];
        atomicAdd(&stats[rep * 128 + c], s);
    } else if (w == 1) {
        float q = 0.f;
        #pragma unroll
        for (int ww = 0; ww < 8; ww++) q += qbuf[ww][c];
        atomicAdd(&stats[rep * 128 + 64 + c], q);
    }
}

// ---------------- subgraph mean (only for the initial x) ----------------
__global__ void smean_kernel(const float* __restrict__ hin, float* __restrict__ xsum) {
    __shared__ float red[16][64];
    int t = threadIdx.x;
    int w = t >> 6, c = t & 63;
    int n = blockIdx.x;
    int base = n * 64 + c;
    float s = 0.f;
    #pragma unroll 8
    for (int j = 0; j < 32; j++) {
        int si = w * 32 + j;
        s += hin[si * 32768 + base];
    }
    red[w][c] = s;
    __syncthreads();
    if (w == 0) {
        float tot = 0.f;
        #pragma unroll
        for (int ww = 0; ww < 16; ww++) tot += red[ww][c];
        xsum[base] = tot * (1.f / 512.f);
    }
}

// ---------------- fold BN stats into per-column scale/shift ----------------
__global__ void finalize_kernel(const float* __restrict__ stB, const float* __restrict__ stS,
                                const float* __restrict__ gB, const float* __restrict__ bB,
                                const float* __restrict__ gS, const float* __restrict__ bS,
                                float* __restrict__ bnp) {
    int c = threadIdx.x;
    float sb = 0.f, qb = 0.f, ss = 0.f, qs = 0.f;
    for (int r = 0; r < 32; r++) {
        sb += stB[r * 128 + c];
        qb += stB[r * 128 + 64 + c];
        ss += stS[r * 128 + c];
        qs += stS[r * 128 + 64 + c];
    }
    float muB = sb * (1.f / 262144.f);
    float varB = qb * (1.f / 262144.f) - muB * muB;
    float scB = gB[c] * rsqrtf(varB + 1e-5f);
    bnp[c] = scB;
    bnp[64 + c] = bB[c] - muB * scB;
    float muS = ss * (1.f / 512.f);
    float varS = qs * (1.f / 512.f) - muS * muS;
    float scS = gS[c] * rsqrtf(varS + 1e-5f);
    bnp[128 + c] = scS;
    bnp[192 + c] = bS[c] - muS * scS;
}

// ---------------- h = relu(bn(h1)+bn(h2)[n]) fused with next-layer smean ----
// block = one original node n (512 blocks), 1024 threads = 16 waves.
// lane l: cols c4..c4+3 (c4=(l&15)*4), row-subgroup r=l>>4. Wave w covers
// subgraphs w*32 + j*4 + r, j=0..7.
__global__ __launch_bounds__(1024) void combine_smean_kernel(
    const float* __restrict__ h1, const float* __restrict__ h2,
    const float* __restrict__ bnp, float* __restrict__ hout, float* __restrict__ xsum)
{
    __shared__ float red[16][64];
    int t = threadIdx.x;
    int w = t >> 6;
    int l = t & 63;
    int c4 = (l & 15) * 4;
    int r = l >> 4;
    int n = blockIdx.x;

    float4 sB = *(const float4*)(bnp + c4);
    float4 hB = *(const float4*)(bnp + 64 + c4);
    float4 sS = *(const float4*)(bnp + 128 + c4);
    float4 hS = *(const float4*)(bnp + 192 + c4);
    float4 b2 = *(const float4*)(h2 + n * 64 + c4);
    float bx = b2.x * sS.x + hS.x;
    float by = b2.y * sS.y + hS.y;
    float bz = b2.z * sS.z + hS.z;
    float bw = b2.w * sS.w + hS.w;

    float4 acc = make_float4(0.f, 0.f, 0.f, 0.f);
    #pragma unroll
    for (int j = 0; j < 8; j++) {
        int si = w * 32 + j * 4 + r;
        size_t base = (size_t)(si * 512 + n) * 64 + c4;
        float4 a = *(const float4*)(h1 + base);
        float4 v;
        v.x = fmaxf(a.x * sB.x + hB.x + bx, 0.f);
        v.y = fmaxf(a.y * sB.y + hB.y + by, 0.f);
        v.z = fmaxf(a.z * sB.z + hB.z + bz, 0.f);
        v.w = fmaxf(a.w * sB.w + hB.w + bw, 0.f);
        *(float4*)(hout + base) = v;
        acc.x += v.x; acc.y += v.y; acc.z += v.z; acc.w += v.w;
    }
    // combine the 4 row-subgroups (lanes l, l^16, l^32, l^48 share c4)
    acc.x += __shfl_xor(acc.x, 16, 64); acc.y += __shfl_xor(acc.y, 16, 64);
    acc.z += __shfl_xor(acc.z, 16, 64); acc.w += __shfl_xor(acc.w, 16, 64);
    acc.x += __shfl_xor(acc.x, 32, 64); acc.y += __shfl_xor(acc.y, 32, 64);
    acc.z += __shfl_xor(acc.z, 32, 64); acc.w += __shfl_xor(acc.w, 32, 64);
    if (l < 16) {
        red[w][c4 + 0] = acc.x;
        red[w][c4 + 1] = acc.y;
        red[w][c4 + 2] = acc.z;
        red[w][c4 + 3] = acc.w;
    }
    __syncthreads();
    if (t < 64) {
        float tot = 0.f;
        #pragma unroll
        for (int ww = 0; ww < 16; ww++) tot += red[ww][t];
        xsum[n * 64 + t] = tot * (1.f / 512.f);
    }
}

// ---------------- head ----------------
__global__ void head_kernel(const float* __restrict__ xs, const float* __restrict__ W1,
                            const float* __restrict__ b1, const float* __restrict__ W2,
                            const float* __restrict__ b2, float* __restrict__ out) {
    __shared__ float z[64];
    __shared__ float hid[128];
    int t = threadIdx.x;
    int n = blockIdx.x;
    if (t < 64) {
        float v = xs[n * 64 + t];
        float m = v;
        for (int off = 32; off >= 1; off >>= 1) m = fmaxf(m, __shfl_xor(m, off, 64));
        float e = expf(v - m);
        float s = e;
        for (int off = 32; off >= 1; off >>= 1) s += __shfl_xor(s, off, 64);
        z[t] = v - m - logf(s);
    }
    __syncthreads();
    {
        float acc = b1[t];
        const float* wrow = W1 + t * 64;
        #pragma unroll 8
        for (int k = 0; k < 64; k++) acc += z[k] * wrow[k];
        hid[t] = fmaxf(acc, 0.f);
    }
    __syncthreads();
    if (t < 10) {
        float o = b2[t];
        const float* wrow = W2 + t * 128;
        #pragma unroll 8
        for (int j = 0; j < 128; j++) o += hid[j] * wrow[j];
        out[n * 10 + t] = o;
    }
}

extern "C" void kernel_launch(void* const* d_in, const int* in_sizes, int n_in,
                              void* d_out, int out_size, void* d_ws, size_t ws_size,
                              hipStream_t stream) {
    const float* x       = (const float*)d_in[0];
    const float* Wrel    = (const float*)d_in[1];
    const float* brel    = (const float*)d_in[2];
    const float* Wroot   = (const float*)d_in[3];
    const float* bn_g    = (const float*)d_in[4];
    const float* bn_b    = (const float*)d_in[5];
    const float* Wrel_s  = (const float*)d_in[6];
    const float* brel_s  = (const float*)d_in[7];
    const float* Wroot_s = (const float*)d_in[8];
    const float* bns_g   = (const float*)d_in[9];
    const float* bns_b   = (const float*)d_in[10];
    const float* W1      = (const float*)d_in[11];
    const float* b1      = (const float*)d_in[12];
    const float* W2      = (const float*)d_in[13];
    const float* b2      = (const float*)d_in[14];
    const int* ei        = (const int*)d_in[15];
    const int* oei       = (const int*)d_in[16];
    float* out = (float*)d_out;

    char* ws = (char*)d_ws;
    size_t off = 0;
    auto alloc = [&](size_t bytes) -> void* {
        void* p = ws + off;
        off = (off + bytes + 255) & ~(size_t)255;
        return p;
    };
    float* h     = (float*)alloc((size_t)NT * 64 * 4);
    float* h1    = (float*)alloc((size_t)NT * 64 * 4);
    float* xsum  = (float*)alloc(NS * 64 * 4);
    float* h2    = (float*)alloc(NS * 64 * 4);
    float* stats = (float*)alloc(NLAYER * 2 * 4096 * 4);
    float* bnp   = (float*)alloc(256 * 4);
    int* rowptr  = (int*)alloc((size_t)(NT + 1) * 4);
    int* cursor  = (int*)alloc((size_t)NT * 4);
    int* srcs    = (int*)alloc((size_t)ES * 4);
    int* bsum    = (int*)alloc(256 * 4);
    int* rowptrS = (int*)alloc(513 * 4);
    int* srcsS   = (int*)alloc(EO * 4);
    (void)ws_size; (void)in_sizes; (void)n_in; (void)out_size;

    hipMemsetAsync(cursor, 0, (size_t)NT * 4, stream);
    hipMemsetAsync(stats, 0, (size_t)NLAYER * 2 * 4096 * 4, stream);

    hist_kernel<<<ES / 256, 256, 0, stream>>>(ei + ES, cursor);
    scan1_kernel<<<NT / 1024, 1024, 0, stream>>>(cursor, rowptr, bsum);
    scan2_kernel<<<1, 256, 0, stream>>>(bsum);
    scan3_kernel<<<NT / 1024, 1024, 0, stream>>>(rowptr, bsum, cursor);
    scatter_kernel<<<ES / 256, 256, 0, stream>>>(ei, cursor, srcs);
    small_csr_kernel<<<1, 1024, 0, stream>>>(oei, rowptrS, srcsS);

    smean_kernel<<<NS, 1024, 0, stream>>>(x, xsum);   // xsum of layer-0 input

    for (int i = 0; i < NLAYER; i++) {
        const float* hin = (i == 0) ? x : h;
        float* stB = stats + i * 8192;
        float* stS = stB + 4096;
        gconv_mfma_kernel<<<NT / 64, 256, 0, stream>>>(hin, rowptr, srcs,
            Wrel + i * 4096, Wroot + i * 4096, brel + i * 64, h1, stB);
        gconv_kernel<<<NS / 32, 512, 0, stream>>>(xsum, rowptrS, srcsS,
            Wrel_s + i * 4096, Wroot_s + i * 4096, brel_s + i * 64, h2, stS);
        finalize_kernel<<<1, 64, 0, stream>>>(stB, stS, bn_g + i * 64, bn_b + i * 64,
                                              bns_g + i * 64, bns_b + i * 64, bnp);
        // writes new h AND its subgraph-mean (used by next layer's small gconv / head)
        combine_smean_kernel<<<NS, 1024, 0, stream>>>(h1, h2, bnp, h, xsum);
    }
    head_kernel<<<NS, 128, 0, stream>>>(xsum, W1, b1, W2, b2, out);
}